// Round 7
// baseline (521.540 us; speedup 1.0000x reference)
//
#include <hip/hip_runtime.h>
#include <math.h>

#define F_    16
#define NROW  2000
#define NL    500
#define D     32
#define ROWS  (F_*NROW)   // 32000
#define SLOPE 0.2f
#define CAP   128         // nz capacity per row (mean ~40, 14 sigma safe)
#define LCAP  256         // compaction scratch (+dump slot)
#define NBLK  512         // 2 blocks/CU * 256 CUs -- co-resident by launch_bounds
#define TPB   256

typedef float f4 __attribute__((ext_vector_type(4)));

// ---- LDS overlay: one phase live at a time (barriers separate phases) ------
struct PA { float sw3[D*33]; float sb3[D]; float sal[D]; float sar[D];
            unsigned short shj[4][LCAP+8]; };
struct PB { float red[8][D]; float she[8][CAP]; unsigned short shjj[8][CAP]; };
struct PC { float sw1[D*33]; float sb1[D]; float ssum[D]; };
struct PD { float swih[96*33]; float sw2[D*33]; float sbg[96];
            float sb2[D]; float slg[D]; float slb[D];
            unsigned short jl[8][CAP]; float aggsh[8][D]; float s2sh[8][D]; };
union SMU { PA a; PB b; PC c; PD d; };

// ---- single-use grid barrier (counters zeroed by memset each launch) -------
__device__ __forceinline__ void gridbar(int* bar, int id) {
    __syncthreads();
    __threadfence();   // flush this thread's global writes to device scope
    if (threadIdx.x == 0) {
        __hip_atomic_fetch_add(bar + id * 32, 1, __ATOMIC_ACQ_REL,
                               __HIP_MEMORY_SCOPE_AGENT);
        while (__hip_atomic_load(bar + id * 32, __ATOMIC_ACQUIRE,
                                 __HIP_MEMORY_SCOPE_AGENT) < NBLK)
            __builtin_amdgcn_s_sleep(2);
    }
    __syncthreads();
    __threadfence();   // acquire side for all threads' subsequent loads
}

__global__ __launch_bounds__(TPB, 2) void mega(
    const float* __restrict__ state, const float* __restrict__ left,
    const float* __restrict__ adj,
    const float* __restrict__ w3, const float* __restrict__ b3,
    const float* __restrict__ attn_w, const float* __restrict__ w4,
    const float* __restrict__ b4,
    const float* __restrict__ w1, const float* __restrict__ b1,
    const float* __restrict__ w_ih, const float* __restrict__ b_ih,
    const float* __restrict__ b_hh,
    const float* __restrict__ ln_g, const float* __restrict__ ln_b,
    const float* __restrict__ w2, const float* __restrict__ b2,
    float* __restrict__ out,
    int* bar, float* g, float* h, float* st, float* s_l, float* s_r,
    float* w4t, float* psum, int* nzc, unsigned short* nzi)
{
    __shared__ SMU sm;
    int q = blockIdx.x;
    int t = threadIdx.x;
    int grp = t >> 5, lane = t & 31;       // 8 groups of 32
    int wv = t >> 6, lane64 = t & 63;      // 4 waves of 64

    // batch-aligned partition: 32 blocks/batch; slices of 63 (first 16) / 62
    int b  = q >> 5, ss = q & 31;
    int lo = (ss < 16) ? ss * 63 : 16 * 63 + (ss - 16) * 62;
    int n  = (ss < 16) ? 63 : 62;
    int rowbase = b * NROW + lo;

    // ================= Phase A: k1 (g, s_l, s_r) + w4t + adj compact ========
    for (int k = t; k < D*D; k += TPB) sm.a.sw3[(k>>5)*33 + (k&31)] = w3[k];
    if (t < D) { sm.a.sb3[t] = b3[t]; sm.a.sal[t] = attn_w[t]; sm.a.sar[t] = attn_w[D+t]; }
    __syncthreads();

    for (int it = 0; it < 8; ++it) {
        int r = it * 8 + grp;
        if (r < n) {
            int row = rowbase + r;
            int i = lo + r;
            const float* xrow = (i < NL) ? (left  + ((size_t)b * NL + i) * D)
                                         : (state + ((size_t)b * (NROW-NL) + (i-NL)) * D);
            float x = xrow[lane];
            float acc = sm.a.sb3[lane];
#pragma unroll
            for (int k = 0; k < D; ++k)
                acc += __shfl(x, k, 32) * sm.a.sw3[lane*33 + k];
            g[(size_t)row * D + lane] = acc;
            float pl = acc * sm.a.sal[lane], pr = acc * sm.a.sar[lane];
#pragma unroll
            for (int m = 16; m >= 1; m >>= 1) {
                pl += __shfl_xor(pl, m, 32);
                pr += __shfl_xor(pr, m, 32);
            }
            if (lane == 0) { s_l[row] = pl; s_r[row] = pr; }
        }
    }

    // w4 transpose (each global element exactly once)
    { int k = q * TPB + t;
      if (k < D * NROW) { int o = k / NROW, j = k - o * NROW; w4t[j*D + o] = w4[k]; } }

    // adj stream + compaction, wave-per-row
    unsigned long long lmask = (1ull << lane64) - 1ull;
    for (int rr = wv; rr < n; rr += 4) {
        int row = rowbase + rr;
        const f4* mrow = reinterpret_cast<const f4*>(adj + (size_t)row * NROW);
        f4 v[8];
#pragma unroll
        for (int it = 0; it < 7; ++it)
            v[it] = __builtin_nontemporal_load(mrow + it * 64 + lane64);
        v[7] = (f4)(0.f);
        if (448 + lane64 < NROW/4) v[7] = __builtin_nontemporal_load(mrow + 448 + lane64);

        int c = 0;
#pragma unroll
        for (int it = 0; it < 8; ++it)
            c += (v[it][0]!=0.f) + (v[it][1]!=0.f) + (v[it][2]!=0.f) + (v[it][3]!=0.f);
        int inc = c;
#pragma unroll
        for (int off = 1; off < 64; off <<= 1) {
            int nn = __shfl_up(inc, off, 64);
            inc += (lane64 >= off) ? nn : 0;
        }
        int pos = inc - c;
        int cnt = __shfl(inc, 63, 64);
#pragma unroll
        for (int it = 0; it < 8; ++it) {
            int jb = (it * 64 + lane64) * 4;
#pragma unroll
            for (int cc = 0; cc < 4; ++cc) {
                int hit = (v[it][cc] != 0.f);
                int tgt = (hit && pos < LCAP) ? pos : LCAP;
                sm.a.shj[wv][tgt] = (unsigned short)(jb + cc);
                pos += hit;
            }
        }
        int cc2 = (cnt < CAP) ? cnt : CAP;
        for (int k = lane64; k < cc2; k += 64)
            nzi[(size_t)row * CAP + k] = sm.a.shj[wv][k];
        if (lane64 == 0) nzc[row] = cc2;
    }

    gridbar(bar, 0);   // s_l/s_r (all batches) ready; w4t ready

    // ================= Phase B: h + per-block softmax partial sums ==========
    float esum = 0.f;
    for (int it = 0; it < 8; ++it) {
        int r = it * 8 + grp;
        if (r < n) {
            int row = rowbase + r;
            int i = lo + r;
            int cnt = nzc[row];
            const unsigned short* lst = nzi + (size_t)row * CAP;
            const float* slb = s_l + (size_t)b * NROW;
            const float* srr = s_r + (size_t)(i & 15) * NROW;
            for (int k = lane; k < cnt; k += 32) {
                int j = lst[k];
                sm.b.shjj[grp][k] = (unsigned short)j;
                float e = slb[j] + srr[j];
                sm.b.she[grp][k] = (e > 0.f) ? e : SLOPE * e;
            }
            float acc = 0.f;
            int k = 0;
            for (; k + 4 <= cnt; k += 4) {
                int j0 = sm.b.shjj[grp][k],   j1 = sm.b.shjj[grp][k+1];
                int j2 = sm.b.shjj[grp][k+2], j3 = sm.b.shjj[grp][k+3];
                acc += sm.b.she[grp][k]   * w4t[j0*D + lane]
                     + sm.b.she[grp][k+1] * w4t[j1*D + lane]
                     + sm.b.she[grp][k+2] * w4t[j2*D + lane]
                     + sm.b.she[grp][k+3] * w4t[j3*D + lane];
            }
            for (; k < cnt; ++k)
                acc += sm.b.she[grp][k] * w4t[sm.b.shjj[grp][k]*D + lane];
            float hv = acc + b4[lane];
            hv = (hv > 0.f) ? hv : SLOPE * hv;
            h[(size_t)row * D + lane] = hv;
            esum += expf(hv);
        }
    }
    sm.b.red[grp][lane] = esum;
    __syncthreads();
    if (t < D) {
        float tot = 0.f;
#pragma unroll
        for (int k = 0; k < 8; ++k) tot += sm.b.red[k][t];
        psum[q * D + t] = tot;
    }

    gridbar(bar, 1);   // all h / psum ready

    // ================= Phase C: st = (softmax(h)*g) @ w1^T + b1 =============
    for (int k = t; k < D*D; k += TPB) sm.c.sw1[(k>>5)*33 + (k&31)] = w1[k];
    if (t < D) {
        sm.c.sb1[t] = b1[t];
        float tot = 0.f;
#pragma unroll
        for (int s = 0; s < 32; ++s) tot += psum[(b * 32 + s) * D + t];
        sm.c.ssum[t] = tot;
    }
    __syncthreads();
    for (int it = 0; it < 8; ++it) {
        int r = it * 8 + grp;
        if (r < n) {
            size_t row = (size_t)rowbase + r;
            float p = (expf(h[row*D + lane]) / sm.c.ssum[lane]) * g[row*D + lane];
            float acc = sm.c.sb1[lane];
#pragma unroll
            for (int k = 0; k < D; ++k)
                acc += __shfl(p, k, 32) * sm.c.sw1[lane*33 + k];
            st[row*D + lane] = acc;
        }
    }

    gridbar(bar, 2);   // all st ready

    // ================= Phase D: agg gather + LN + gates + final matvec ======
    for (int k = t; k < 96*D; k += TPB) sm.d.swih[(k/D)*33 + (k%D)] = w_ih[k];
    for (int k = t; k < D*D;  k += TPB) sm.d.sw2 [(k/D)*33 + (k%D)] = w2[k];
    if (t < 96) sm.d.sbg[t] = b_ih[t] + b_hh[t];
    if (t < D) { sm.d.sb2[t] = b2[t]; sm.d.slg[t] = ln_g[t]; sm.d.slb[t] = ln_b[t]; }
    __syncthreads();

    const float* stb = st + (size_t)b * NROW * D;
    for (int it = 0; it < 8; ++it) {
        int r = it * 8 + grp;
        if (r < n) {
            int row = rowbase + r;
            int cnt = nzc[row];
            const unsigned short* lst = nzi + (size_t)row * CAP;
            for (int k = lane; k < cnt; k += 32) sm.d.jl[grp][k] = lst[k];

            float agg = 0.f;
            int k = 0;
            for (; k + 8 <= cnt; k += 8) {
                int j0 = sm.d.jl[grp][k],   j1 = sm.d.jl[grp][k+1];
                int j2 = sm.d.jl[grp][k+2], j3 = sm.d.jl[grp][k+3];
                int j4 = sm.d.jl[grp][k+4], j5 = sm.d.jl[grp][k+5];
                int j6 = sm.d.jl[grp][k+6], j7 = sm.d.jl[grp][k+7];
                float a0 = stb[j0*D + lane], a1 = stb[j1*D + lane];
                float a2 = stb[j2*D + lane], a3 = stb[j3*D + lane];
                float a4 = stb[j4*D + lane], a5 = stb[j5*D + lane];
                float a6 = stb[j6*D + lane], a7 = stb[j7*D + lane];
                agg += ((a0+a1) + (a2+a3)) + ((a4+a5) + (a6+a7));
            }
            for (; k < cnt; ++k) agg += stb[sm.d.jl[grp][k]*D + lane];

            float sv = st[(size_t)row * D + lane];
            float sum = sv;
#pragma unroll
            for (int m = 16; m >= 1; m >>= 1) sum += __shfl_xor(sum, m, 32);
            float mean = sum * (1.f / D);
            float dd = sv - mean;
            float vs = dd * dd;
#pragma unroll
            for (int m = 16; m >= 1; m >>= 1) vs += __shfl_xor(vs, m, 32);
            float inv = 1.f / sqrtf(vs * (1.f / D) + 1e-6f);
            float nx = sm.d.slg[lane] * dd * inv + sm.d.slb[lane];

            sm.d.aggsh[grp][lane] = agg;   // same-wave LDS, no barrier needed

            float gi = sm.d.sbg[lane], gf = sm.d.sbg[lane+32], gg = sm.d.sbg[lane+64];
#pragma unroll
            for (int d = 0; d < D; ++d) {
                float a = sm.d.aggsh[grp][d];
                gi += sm.d.swih[lane*33 + d]      * a;
                gf += sm.d.swih[(lane+32)*33 + d] * a;
                gg += sm.d.swih[(lane+64)*33 + d] * a;
            }
            float ig  = 1.f / (1.f + expf(-gi));
            float fg  = 1.f / (1.f + expf(-gf));
            float g_g = tanhf(gg);
            float s2  = sv + fg * nx + ig * g_g;

            sm.d.s2sh[grp][lane] = s2;     // same-wave LDS

            float acc = sm.d.sb2[lane];
#pragma unroll
            for (int qq = 0; qq < D; ++qq) acc += sm.d.sw2[lane*33 + qq] * sm.d.s2sh[grp][qq];
            out[(size_t)row * D + lane] = acc;
        }
    }
}

// ---------------------------------------------------------------------------
extern "C" void kernel_launch(void* const* d_in, const int* in_sizes, int n_in,
                              void* d_out, int out_size, void* d_ws, size_t ws_size,
                              hipStream_t stream)
{
    const float* state  = (const float*)d_in[0];
    const float* left   = (const float*)d_in[1];
    const float* adj    = (const float*)d_in[2];
    const float* w3     = (const float*)d_in[3];
    const float* b3     = (const float*)d_in[4];
    const float* attn_w = (const float*)d_in[5];
    const float* w4     = (const float*)d_in[6];
    const float* b4     = (const float*)d_in[7];
    const float* w1     = (const float*)d_in[8];
    const float* b1     = (const float*)d_in[9];
    const float* w_ih   = (const float*)d_in[10];
    // d_in[11] = w_hh: unused by the reference math (only b_hh enters gates)
    const float* b_ih   = (const float*)d_in[12];
    const float* b_hh   = (const float*)d_in[13];
    const float* ln_g   = (const float*)d_in[14];
    const float* ln_b   = (const float*)d_in[15];
    const float* w2     = (const float*)d_in[16];
    const float* b2     = (const float*)d_in[17];
    float* out = (float*)d_out;

    // workspace layout
    int*   bar  = (int*)d_ws;                            // 4*32 ints (zeroed)
    float* g    = (float*)((char*)d_ws + 1024);          // ROWS*D
    float* h    = g  + (size_t)ROWS * D;                 // ROWS*D
    float* st   = h  + (size_t)ROWS * D;                 // ROWS*D
    float* s_l  = st + (size_t)ROWS * D;                 // ROWS
    float* s_r  = s_l + ROWS;                            // ROWS
    float* w4t  = s_r + ROWS;                            // NROW*D
    float* psum = w4t + (size_t)NROW * D;                // NBLK*D
    int*   nzc  = (int*)(psum + NBLK * D);               // ROWS
    unsigned short* nzi = (unsigned short*)(nzc + ROWS); // ROWS*CAP

    hipMemsetAsync(bar, 0, 1024, stream);
    mega<<<dim3(NBLK), dim3(TPB), 0, stream>>>(
        state, left, adj, w3, b3, attn_w, w4, b4, w1, b1,
        w_ih, b_ih, b_hh, ln_g, ln_b, w2, b2, out,
        bar, g, h, st, s_l, s_r, w4t, psum, nzc, nzi);
}

// Round 8
// 154.908 us; speedup vs baseline: 3.3668x; 3.3668x over previous
//
#include <hip/hip_runtime.h>
#include <math.h>

#define F_    16
#define NROW  2000
#define NL    500
#define D     32
#define ROWS  (F_*NROW)       // 32000
#define SLOPE 0.2f
#define CAP   128             // nz capacity per row (mean ~40, 14 sigma safe)
#define NF4   (ROWS*NROW/4)   // 16,000,000 float4 elements in adj
#define SBLK  2048            // stream grid
#define STRD  (SBLK*256)

typedef float f4 __attribute__((ext_vector_type(4)));

// ---------------- K1: g = x@w3^T+b3 ; s_l,s_r ; (+w4 transpose blocks) ------
__global__ __launch_bounds__(256) void k1_g(
    const float* __restrict__ state, const float* __restrict__ left,
    const float* __restrict__ w3, const float* __restrict__ b3,
    const float* __restrict__ attn_w, const float* __restrict__ w4,
    float* __restrict__ g, float* __restrict__ s_l, float* __restrict__ s_r,
    float* __restrict__ w4t)
{
    int bid = blockIdx.x;
    int t = threadIdx.x;
    if (bid >= ROWS/8) {           // transpose tail: w4t[j][o] = w4[o][j]
        int k = (bid - ROWS/8) * 256 + t;
        if (k < D * NROW) {
            int o = k / NROW, j = k - o * NROW;
            w4t[j * D + o] = w4[k];
        }
        return;
    }
    __shared__ float sw3[D*33];
    __shared__ float sb3[D], sal[D], sar[D];
    for (int k = t; k < D*D; k += 256) sw3[(k>>5)*33 + (k&31)] = w3[k];
    if (t < D) { sb3[t] = b3[t]; sal[t] = attn_w[t]; sar[t] = attn_w[D + t]; }
    __syncthreads();
    int grp = t >> 5, lane = t & 31;
    int row = bid * 8 + grp;
    int b = row / NROW, i = row - b * NROW;
    const float* xrow = (i < NL) ? (left  + ((size_t)b * NL + i) * D)
                                 : (state + ((size_t)b * (NROW - NL) + (i - NL)) * D);
    float x = xrow[lane];
    float acc = sb3[lane];
#pragma unroll
    for (int k = 0; k < D; ++k)
        acc += __shfl(x, k, 32) * sw3[lane*33 + k];
    g[(size_t)row * D + lane] = acc;
    float pl = acc * sal[lane], pr = acc * sar[lane];
#pragma unroll
    for (int m = 16; m >= 1; m >>= 1) {
        pl += __shfl_xor(pl, m, 32);
        pr += __shfl_xor(pr, m, 32);
    }
    if (lane == 0) { s_l[row] = pl; s_r[row] = pr; }
}

// ---------------- K2a: FLAT grid-stride stream + atomic compaction ----------
// The 6.3 TB/s access pattern: consecutive threads read consecutive float4s.
// Per wave-iter: <=2 row-groups; slots reserved with one atomicAdd per group.
// List order is atomic-arrival order -- downstream only SUMS the lists.
__global__ __launch_bounds__(256) void k2a_flat(
    const float* __restrict__ adj,
    int* __restrict__ nzc, unsigned short* __restrict__ nzi)
{
    const f4* adj4 = reinterpret_cast<const f4*>(adj);
    int tid = blockIdx.x * 256 + threadIdx.x;
    int lane = threadIdx.x & 63;
    unsigned long long lmask = (1ull << lane) - 1ull;

    for (int idx = tid; idx < NF4; idx += STRD) {
        f4 v = adj4[idx];
        int row = idx / 500;                    // 500 float4 per row
        int jb  = (idx - row * 500) * 4;        // column of v[0]
        int h0 = (v[0] != 0.f), h1 = (v[1] != 0.f);
        int h2 = (v[2] != 0.f), h3 = (v[3] != 0.f);
        int nh = h0 + h1 + h2 + h3;

        // group lanes by row (<=2 distinct rows per wave-iter)
        int row0 = __shfl(row, 0, 64);
        unsigned long long g0 = __ballot(row == row0);
        unsigned long long act = __ballot(1);
        unsigned long long same = (row == row0) ? g0 : (act & ~g0);

        // bit-plane masked prefix / total of nh over my group
        unsigned long long p0 = __ballot(nh & 1);
        unsigned long long p1 = __ballot(nh & 2);
        unsigned long long p2 = __ballot(nh & 4);
        unsigned long long pm = same & lmask;
        int prefix = __popcll(p0 & pm) + 2*__popcll(p1 & pm) + 4*__popcll(p2 & pm);
        int total  = __popcll(p0 & same) + 2*__popcll(p1 & same) + 4*__popcll(p2 & same);

        int lead = (int)__builtin_ctzll(same);
        int base = 0;
        if (lane == lead && total > 0)
            base = atomicAdd(&nzc[row], total);
        base = __shfl(base, lead, 64);

        int slot = base + prefix;
        unsigned short* nrow = nzi + (size_t)row * CAP;
        if (h0) { if (slot < CAP) nrow[slot] = (unsigned short)(jb);     slot++; }
        if (h1) { if (slot < CAP) nrow[slot] = (unsigned short)(jb + 1); slot++; }
        if (h2) { if (slot < CAP) nrow[slot] = (unsigned short)(jb + 2); slot++; }
        if (h3) { if (slot < CAP) nrow[slot] = (unsigned short)(jb + 3); slot++; }
    }
}

// ---------------- K2b: h from nz lists + softmax partials (atomic) ----------
// 32-lane group per row; 8 rows/block, 4000 blocks. Folds old k3a.
__global__ __launch_bounds__(256) void k2b_h(
    const float* __restrict__ s_l, const float* __restrict__ s_r,
    const float* __restrict__ w4t, const float* __restrict__ b4,
    const int* __restrict__ nzc, const unsigned short* __restrict__ nzi,
    float* __restrict__ h, float* __restrict__ psum)
{
    __shared__ float sh_e[8][CAP];
    __shared__ unsigned short sh_jj[8][CAP];
    __shared__ float red[8][D];
    int t = threadIdx.x;
    int grp = t >> 5, lane = t & 31;
    int row = blockIdx.x * 8 + grp;
    int b = row / NROW, i = row - b * NROW;
    int r = i & 15;
    int cnt = nzc[row]; cnt = (cnt < CAP) ? cnt : CAP;
    const unsigned short* lst = nzi + (size_t)row * CAP;
    const float* slb = s_l + (size_t)b * NROW;
    const float* srr = s_r + (size_t)r * NROW;
    for (int k = lane; k < cnt; k += 32) {
        int j = lst[k];
        sh_jj[grp][k] = (unsigned short)j;
        float e = slb[j] + srr[j];
        sh_e[grp][k] = (e > 0.f) ? e : SLOPE * e;
    }
    // per-group LDS written+read by the same wave: no barrier needed
    float acc = 0.f;
    int k = 0;
    for (; k + 4 <= cnt; k += 4) {
        int j0 = sh_jj[grp][k],   j1 = sh_jj[grp][k+1];
        int j2 = sh_jj[grp][k+2], j3 = sh_jj[grp][k+3];
        acc += sh_e[grp][k]   * w4t[j0*D + lane] + sh_e[grp][k+1] * w4t[j1*D + lane]
             + sh_e[grp][k+2] * w4t[j2*D + lane] + sh_e[grp][k+3] * w4t[j3*D + lane];
    }
    for (; k < cnt; ++k)
        acc += sh_e[grp][k] * w4t[sh_jj[grp][k]*D + lane];
    float hv = acc + b4[lane];
    hv = (hv > 0.f) ? hv : SLOPE * hv;
    h[(size_t)row * D + lane] = hv;
    red[grp][lane] = expf(hv);
    __syncthreads();
    if (t < D) {
        float tot = 0.f;
#pragma unroll
        for (int kk = 0; kk < 8; ++kk) tot += red[kk][t];
        atomicAdd(&psum[b * D + t], tot);
    }
}

// ---------------- K3b: st = (softmax(h)*g) @ w1^T + b1 -----------------------
__global__ __launch_bounds__(256) void k3b_st(
    const float* __restrict__ h, const float* __restrict__ g,
    const float* __restrict__ psum,
    const float* __restrict__ w1, const float* __restrict__ b1,
    float* __restrict__ st)
{
    __shared__ float sw1[D*33], sb1[D], ssum[D];
    int t = threadIdx.x;
    int bid = blockIdx.x;
    int b = bid / 250;
    for (int k = t; k < D*D; k += 256) sw1[(k>>5)*33 + (k&31)] = w1[k];
    if (t < D) { sb1[t] = b1[t]; ssum[t] = psum[b * D + t]; }
    __syncthreads();
    int grp = t >> 5, lane = t & 31;
    size_t row = (size_t)bid * 8 + grp;
    float p = (expf(h[row * D + lane]) / ssum[lane]) * g[row * D + lane];
    float acc = sb1[lane];
#pragma unroll
    for (int k = 0; k < D; ++k)
        acc += __shfl(p, k, 32) * sw1[lane*33 + k];
    st[row * D + lane] = acc;
}

// ---------------- K4: agg gather + LN + gates + c1 + final matvec ------------
__global__ __launch_bounds__(256) void k4_final(
    const float* __restrict__ st,
    const int* __restrict__ nzc, const unsigned short* __restrict__ nzi,
    const float* __restrict__ w_ih, const float* __restrict__ b_ih,
    const float* __restrict__ b_hh,
    const float* __restrict__ ln_g, const float* __restrict__ ln_b,
    const float* __restrict__ w2, const float* __restrict__ b2,
    float* __restrict__ out)
{
    __shared__ float swih[96*33];          // padded
    __shared__ float sw2[D*33];            // padded
    __shared__ float sbg[96];
    __shared__ float sb2[D], slg[D], slb[D];
    __shared__ unsigned short jl[8][CAP];
    __shared__ float aggsh[8][D];
    __shared__ float s2sh[8][D];

    int t = threadIdx.x;
    for (int k = t; k < 96*D; k += 256) swih[(k/D)*33 + (k%D)] = w_ih[k];
    for (int k = t; k < D*D;  k += 256) sw2 [(k/D)*33 + (k%D)] = w2[k];
    if (t < 96) sbg[t] = b_ih[t] + b_hh[t];
    if (t < D) { sb2[t] = b2[t]; slg[t] = ln_g[t]; slb[t] = ln_b[t]; }

    int grp = t >> 5, lane = t & 31;
    int row = blockIdx.x * 8 + grp;
    int b = row / NROW;
    int cnt = nzc[row]; cnt = (cnt < CAP) ? cnt : CAP;
    const unsigned short* lst = nzi + (size_t)row * CAP;
    for (int k = lane; k < cnt; k += 32) jl[grp][k] = lst[k];
    __syncthreads();   // for the cooperatively staged weights

    const float* stb = st + (size_t)b * NROW * D;
    float agg = 0.f;
    int k = 0;
    for (; k + 8 <= cnt; k += 8) {
        int j0 = jl[grp][k],   j1 = jl[grp][k+1], j2 = jl[grp][k+2], j3 = jl[grp][k+3];
        int j4 = jl[grp][k+4], j5 = jl[grp][k+5], j6 = jl[grp][k+6], j7 = jl[grp][k+7];
        float a0 = stb[j0*D + lane], a1 = stb[j1*D + lane];
        float a2 = stb[j2*D + lane], a3 = stb[j3*D + lane];
        float a4 = stb[j4*D + lane], a5 = stb[j5*D + lane];
        float a6 = stb[j6*D + lane], a7 = stb[j7*D + lane];
        agg += ((a0 + a1) + (a2 + a3)) + ((a4 + a5) + (a6 + a7));
    }
    for (; k < cnt; ++k) agg += stb[jl[grp][k]*D + lane];

    float sv = st[(size_t)row * D + lane];

    float sum = sv;
#pragma unroll
    for (int m = 16; m >= 1; m >>= 1) sum += __shfl_xor(sum, m, 32);
    float mean = sum * (1.f / D);
    float dd = sv - mean;
    float vs = dd * dd;
#pragma unroll
    for (int m = 16; m >= 1; m >>= 1) vs += __shfl_xor(vs, m, 32);
    float inv = 1.f / sqrtf(vs * (1.f / D) + 1e-6f);
    float nx = slg[lane] * dd * inv + slb[lane];

    aggsh[grp][lane] = agg;     // per-group buffer: same-wave ordering only

    float gi = sbg[lane], gf = sbg[lane + 32], gg = sbg[lane + 64];
#pragma unroll
    for (int d = 0; d < D; ++d) {
        float a = aggsh[grp][d];
        gi += swih[lane*33 + d]      * a;
        gf += swih[(lane+32)*33 + d] * a;
        gg += swih[(lane+64)*33 + d] * a;
    }
    float ig  = 1.f / (1.f + expf(-gi));
    float fg  = 1.f / (1.f + expf(-gf));
    float g_g = tanhf(gg);
    float s2  = sv + fg * nx + ig * g_g;

    s2sh[grp][lane] = s2;       // per-group buffer

    float acc = sb2[lane];
#pragma unroll
    for (int q = 0; q < D; ++q) acc += sw2[lane*33 + q] * s2sh[grp][q];
    out[(size_t)row * D + lane] = acc;
}

// ---------------------------------------------------------------------------
extern "C" void kernel_launch(void* const* d_in, const int* in_sizes, int n_in,
                              void* d_out, int out_size, void* d_ws, size_t ws_size,
                              hipStream_t stream)
{
    const float* state  = (const float*)d_in[0];
    const float* left   = (const float*)d_in[1];
    const float* adj    = (const float*)d_in[2];
    const float* w3     = (const float*)d_in[3];
    const float* b3     = (const float*)d_in[4];
    const float* attn_w = (const float*)d_in[5];
    const float* w4     = (const float*)d_in[6];
    const float* b4     = (const float*)d_in[7];
    const float* w1     = (const float*)d_in[8];
    const float* b1     = (const float*)d_in[9];
    const float* w_ih   = (const float*)d_in[10];
    // d_in[11] = w_hh: unused by the reference math (only b_hh enters gates)
    const float* b_ih   = (const float*)d_in[12];
    const float* b_hh   = (const float*)d_in[13];
    const float* ln_g   = (const float*)d_in[14];
    const float* ln_b   = (const float*)d_in[15];
    const float* w2     = (const float*)d_in[16];
    const float* b2     = (const float*)d_in[17];
    float* out = (float*)d_out;

    // workspace layout (~21 MB total)
    float* g    = (float*)d_ws;                 // ROWS*D
    float* h    = g  + (size_t)ROWS * D;        // ROWS*D
    float* st   = h  + (size_t)ROWS * D;        // ROWS*D
    float* s_l  = st + (size_t)ROWS * D;        // ROWS
    float* s_r  = s_l + ROWS;                   // ROWS
    float* w4t  = s_r + ROWS;                   // NROW*D
    int*   nzc  = (int*)(w4t + (size_t)NROW * D);        // ROWS int    (zeroed)
    float* psum = (float*)(nzc + ROWS);                  // F_*D floats (zeroed)
    unsigned short* nzi = (unsigned short*)(psum + F_ * D); // ROWS*CAP u16

    // zero the atomic counters + softmax accumulators (contiguous region)
    hipMemsetAsync(nzc, 0, ROWS * sizeof(int) + F_ * D * sizeof(float), stream);

    k1_g    <<<dim3(ROWS/8 + (D*NROW+255)/256), dim3(256), 0, stream>>>(
                state, left, w3, b3, attn_w, w4, g, s_l, s_r, w4t);
    k2a_flat<<<dim3(SBLK),    dim3(256), 0, stream>>>(adj, nzc, nzi);
    k2b_h   <<<dim3(ROWS/8),  dim3(256), 0, stream>>>(s_l, s_r, w4t, b4, nzc, nzi, h, psum);
    k3b_st  <<<dim3(ROWS/8),  dim3(256), 0, stream>>>(h, g, psum, w1, b1, st);
    k4_final<<<dim3(ROWS/8),  dim3(256), 0, stream>>>(st, nzc, nzi, w_ih, b_ih, b_hh,
                                                      ln_g, ln_b, w2, b2, out);
}